// Round 1
// baseline (141.930 us; speedup 1.0000x reference)
//
#include <hip/hip_runtime.h>
#include <hip/hip_bf16.h>

#define DEV static __device__ __forceinline__

typedef __bf16 bf16x8 __attribute__((ext_vector_type(8)));
typedef float f32x4 __attribute__((ext_vector_type(4)));
typedef unsigned short u16x8 __attribute__((ext_vector_type(8)));
typedef unsigned short u16x4 __attribute__((ext_vector_type(4)));

DEV unsigned short f2bf(float f) {
  unsigned u = __builtin_bit_cast(unsigned, f);
  u += 0x7fffu + ((u >> 16) & 1u);
  return (unsigned short)(u >> 16);
}
DEV float bf2f(unsigned short s) {
  return __builtin_bit_cast(float, (unsigned)s << 16);
}
DEV f32x4 mfma16(bf16x8 a, bf16x8 b, f32x4 c) {
  return __builtin_amdgcn_mfma_f32_16x16x32_bf16(a, b, c, 0, 0, 0);
}

// ---------------- stage 1: channel L2 norm reciprocal ----------------
__global__ __launch_bounds__(256) void rnorm_k(const float* __restrict__ fmap,
                                               float* __restrict__ rn) {
  int tid = threadIdx.x;
  int nl = tid & 63, cq = tid >> 6;
  int b = blockIdx.y;
  int n = blockIdx.x * 64 + nl;
  const float* p = fmap + ((size_t)(b * 512 + cq * 128)) * 1024 + n;
  float s = 0.f;
#pragma unroll 8
  for (int i = 0; i < 128; ++i) { float v = p[i * 1024]; s += v * v; }
  __shared__ float red[4][64];
  red[cq][nl] = s;
  __syncthreads();
  if (tid < 64) {
    float t = red[0][tid] + red[1][tid] + red[2][tid] + red[3][tid];
    // sqrt(512) / max(l2, 1e-12)
    rn[b * 1024 + blockIdx.x * 64 + tid] = 22.62741699796952f / fmaxf(sqrtf(t), 1e-12f);
  }
}

// ---------------- stage 2: normalize + transpose to [b,n,c] bf16 ----------------
__global__ __launch_bounds__(256) void tnorm_k(const float* __restrict__ fmap,
                                               const float* __restrict__ gamma,
                                               const float* __restrict__ rn,
                                               unsigned short* __restrict__ xt) {
  int b = blockIdx.z, c0 = blockIdx.y * 64, n0 = blockIdx.x * 64;
  __shared__ float t[64][65];
  int tx = threadIdx.x, ty = threadIdx.y;  // 64 x 4
#pragma unroll
  for (int i = 0; i < 16; ++i) {
    int r = ty * 16 + i;  // c-local
    t[r][tx] = fmap[((size_t)(b * 512 + c0 + r)) * 1024 + n0 + tx];
  }
  __syncthreads();
  float g = gamma[c0 + tx];
#pragma unroll
  for (int i = 0; i < 16; ++i) {
    int r = ty * 16 + i;  // n-local
    float val = t[tx][r] * rn[b * 1024 + n0 + r] * g;
    xt[((size_t)(b * 1024 + n0 + r)) * 512 + c0 + tx] = f2bf(val);
  }
}

// ---------------- weight f32 -> bf16 ----------------
__global__ __launch_bounds__(256) void cvt_k(const float* __restrict__ src,
                                             unsigned short* __restrict__ dst, int n8) {
  int i = blockIdx.x * 256 + threadIdx.x;
  if (i >= n8) return;
  const float4* s = (const float4*)src;
  float4 a = s[i * 2], b = s[i * 2 + 1];
  u16x8 o;
  o[0] = f2bf(a.x); o[1] = f2bf(a.y); o[2] = f2bf(a.z); o[3] = f2bf(a.w);
  o[4] = f2bf(b.x); o[5] = f2bf(b.y); o[6] = f2bf(b.z); o[7] = f2bf(b.w);
  ((u16x8*)dst)[i] = o;
}

// ---------------- generic 128x128x512 bf16 GEMM: D[i][j] = sum_k A[i][k]*Bt[j][k] ----
// MODE 0: bf16 store D[i][j] at C[i*512 + j]                      (q: [b,n,o])
// MODE 1: bf16 store transposed: C[(b*512 + j)*1024 + (i&1023)]   (v_t: [b,o,n])
// MODE 2: f32 store: C[((j>>10)*512 + i)*1024 + (j&1023)]         (out: [b,c,n])
template <int MODE>
__global__ __launch_bounds__(256) void gemm_k(const unsigned short* __restrict__ A,
                                              const unsigned short* __restrict__ Bt,
                                              void* __restrict__ Cout) {
  __shared__ unsigned short a_lds[128][72];
  __shared__ unsigned short b_lds[128][72];
  int tid = threadIdx.x, lane = tid & 63, wid = tid >> 6;
  int wr = wid >> 1, wc = wid & 1;
  int m0 = blockIdx.y * 128, n0 = blockIdx.x * 128;
  f32x4 acc[4][4] = {};
  for (int kt = 0; kt < 512; kt += 64) {
#pragma unroll
    for (int it = 0; it < 4; ++it) {
      int chunk = it * 256 + tid;           // 0..1023
      int row = chunk >> 3, col = (chunk & 7) * 8;
      *(u16x8*)(&a_lds[row][col]) = *(const u16x8*)(A + (size_t)(m0 + row) * 512 + kt + col);
      *(u16x8*)(&b_lds[row][col]) = *(const u16x8*)(Bt + (size_t)(n0 + row) * 512 + kt + col);
    }
    __syncthreads();
#pragma unroll
    for (int ks = 0; ks < 2; ++ks) {
      bf16x8 af[4], bfr[4];
#pragma unroll
      for (int rt = 0; rt < 4; ++rt)
        af[rt] = __builtin_bit_cast(bf16x8,
            *(const u16x8*)(&a_lds[wr * 64 + rt * 16 + (lane & 15)][ks * 32 + (lane >> 4) * 8]));
#pragma unroll
      for (int ct = 0; ct < 4; ++ct)
        bfr[ct] = __builtin_bit_cast(bf16x8,
            *(const u16x8*)(&b_lds[wc * 64 + ct * 16 + (lane & 15)][ks * 32 + (lane >> 4) * 8]));
#pragma unroll
      for (int rt = 0; rt < 4; ++rt)
#pragma unroll
        for (int ct = 0; ct < 4; ++ct)
          acc[rt][ct] = mfma16(af[rt], bfr[ct], acc[rt][ct]);
    }
    __syncthreads();
  }
  if (MODE == 0) {
    unsigned short* Cp = (unsigned short*)Cout;
#pragma unroll
    for (int rt = 0; rt < 4; ++rt)
#pragma unroll
      for (int ct = 0; ct < 4; ++ct)
#pragma unroll
        for (int r = 0; r < 4; ++r) {
          int row = m0 + wr * 64 + rt * 16 + (lane >> 4) * 4 + r;
          int col = n0 + wc * 64 + ct * 16 + (lane & 15);
          Cp[(size_t)row * 512 + col] = f2bf(acc[rt][ct][r]);
        }
  } else if (MODE == 1) {
    unsigned short* Cp = (unsigned short*)Cout;
    int b = m0 >> 10;
#pragma unroll
    for (int rt = 0; rt < 4; ++rt)
#pragma unroll
      for (int ct = 0; ct < 4; ++ct) {
        int col = n0 + wc * 64 + ct * 16 + (lane & 15);
        int rowb = (m0 & 1023) + wr * 64 + rt * 16 + (lane >> 4) * 4;
        u16x4 pk;
#pragma unroll
        for (int r = 0; r < 4; ++r) pk[r] = f2bf(acc[rt][ct][r]);
        *(u16x4*)(Cp + ((size_t)(b * 512 + col)) * 1024 + rowb) = pk;
      }
  } else {
    float* Cp = (float*)Cout;
    int bb = n0 >> 10;
#pragma unroll
    for (int rt = 0; rt < 4; ++rt)
#pragma unroll
      for (int ct = 0; ct < 4; ++ct)
#pragma unroll
        for (int r = 0; r < 4; ++r) {
          int row = m0 + wr * 64 + rt * 16 + (lane >> 4) * 4 + r;        // c
          int col = (n0 & 1023) + wc * 64 + ct * 16 + (lane & 15);       // n
          Cp[((size_t)(bb * 512 + row)) * 1024 + col] = acc[rt][ct][r];
        }
  }
}

// ---------------- q squared norms (from the bf16 q the MFMA sees) ----------------
__global__ __launch_bounds__(256) void qsq_k(const unsigned short* __restrict__ q,
                                             float* __restrict__ qsq) {
  int idx = blockIdx.x * 256 + threadIdx.x;  // 65536 = b*h*n
  int bh = idx >> 10, n = idx & 1023;
  int b = bh >> 3, h = bh & 7;
  const unsigned short* p = q + ((size_t)(b * 1024 + n)) * 512 + h * 64;
  float s = 0.f;
#pragma unroll
  for (int c8 = 0; c8 < 8; ++c8) {
    u16x8 v = *(const u16x8*)(p + c8 * 8);
#pragma unroll
    for (int e = 0; e < 8; ++e) { float f = bf2f(v[e]); s += f * f; }
  }
  qsq[idx] = s;
}

// ---------------- fused distance-attention ----------------
// grid: (8 q-tiles, 64 bh). block 256 = 4 waves; wave owns 32 q-rows.
__global__ __launch_bounds__(256) void attn_k(const unsigned short* __restrict__ q,
                                              const unsigned short* __restrict__ vt,
                                              const float* __restrict__ qsq,
                                              const float* __restrict__ nkv,
                                              unsigned short* __restrict__ att) {
  const float COEF = 0.18033688011112042f;  // 0.125 * log2(e)
  int bh = blockIdx.y, b = bh >> 3, h = bh & 7;
  int n0 = blockIdx.x * 128;
  int tid = threadIdx.x, lane = tid & 63, wid = tid >> 6;
  __shared__ unsigned short k_lds[128][64];     // swizzled: [row][ (d8^(row&7))*8 + dm ]
  __shared__ unsigned short v_lds[64][128];     // swizzled: [d][ (j8^(d&15))*8 + jm ]
  __shared__ unsigned short p_lds[4][32][128];  // per-wave, swizzled: [il][ (j8^(il&7))*8 + jm ]
  __shared__ float qsq_l[128], ksq_l[128], nk_l[64], nv_l[64], p0_l[128];

  // Q fragments, held in registers for the whole kernel
  bf16x8 qf[2][2];
#pragma unroll
  for (int rt = 0; rt < 2; ++rt)
#pragma unroll
    for (int ks = 0; ks < 2; ++ks) {
      int row = n0 + wid * 32 + rt * 16 + (lane & 15);
      qf[rt][ks] = __builtin_bit_cast(bf16x8,
          *(const u16x8*)(q + ((size_t)(b * 1024 + row)) * 512 + h * 64 + ks * 32 + (lane >> 4) * 8));
    }
  if (tid < 128) qsq_l[tid] = qsq[bh * 1024 + n0 + tid];
  if (tid >= 128 && tid < 192) {
    int d = tid - 128;
    nk_l[d] = nkv[h * 64 + d];
    nv_l[d] = nkv[512 + h * 64 + d];
  }
  __syncthreads();
  // null-token probabilities p0[i] = exp(-(|q_i|^2 + |nk|^2 - 2 q.nk)/8)
  if (tid < 128) {
    const unsigned short* qp = q + ((size_t)(b * 1024 + n0 + tid)) * 512 + h * 64;
    float dot = 0.f, nks = 0.f;
#pragma unroll 8
    for (int d = 0; d < 64; ++d) {
      float qv = bf2f(qp[d]); float nk = nk_l[d];
      dot += qv * nk; nks += nk * nk;
    }
    p0_l[tid] = exp2f((2.f * dot - qsq_l[tid] - nks) * COEF);
  }
  __syncthreads();

  float denom[2][4];
  f32x4 oacc[2][4];
#pragma unroll
  for (int rt = 0; rt < 2; ++rt) {
#pragma unroll
    for (int r = 0; r < 4; ++r) denom[rt][r] = p0_l[wid * 32 + rt * 16 + (lane >> 4) * 4 + r];
#pragma unroll
    for (int dt = 0; dt < 4; ++dt)
#pragma unroll
      for (int r = 0; r < 4; ++r)
        oacc[rt][dt][r] = p0_l[wid * 32 + rt * 16 + (lane >> 4) * 4 + r] * nv_l[dt * 16 + (lane & 15)];
  }

  for (int jt = 0; jt < 8; ++jt) {
    int j0 = jt * 128;
    if (tid < 128) ksq_l[tid] = qsq[bh * 1024 + j0 + tid];
#pragma unroll
    for (int it = 0; it < 4; ++it) {  // stage K tile (k = q)
      int chunk = it * 256 + tid;
      int row = chunk >> 3, d8 = chunk & 7;
      *(u16x8*)(&k_lds[row][(d8 ^ (row & 7)) * 8]) =
          *(const u16x8*)(q + ((size_t)(b * 1024 + j0 + row)) * 512 + h * 64 + d8 * 8);
    }
#pragma unroll
    for (int it = 0; it < 4; ++it) {  // stage V tile (already [d][n])
      int chunk = it * 256 + tid;
      int d = chunk >> 4, j8 = chunk & 15;
      *(u16x8*)(&v_lds[d][(j8 ^ (d & 15)) * 8]) =
          *(const u16x8*)(vt + ((size_t)(b * 512 + h * 64 + d)) * 1024 + j0 + j8 * 8);
    }
    __syncthreads();

    // S = Q K^T over d=64
    f32x4 s[2][8] = {};
#pragma unroll
    for (int ks = 0; ks < 2; ++ks) {
      bf16x8 kf[8];
#pragma unroll
      for (int ct = 0; ct < 8; ++ct) {
        int row = ct * 16 + (lane & 15);
        int d8 = ks * 4 + (lane >> 4);
        kf[ct] = __builtin_bit_cast(bf16x8, *(const u16x8*)(&k_lds[row][(d8 ^ (row & 7)) * 8]));
      }
#pragma unroll
      for (int rt = 0; rt < 2; ++rt)
#pragma unroll
        for (int ct = 0; ct < 8; ++ct)
          s[rt][ct] = mfma16(qf[rt][ks], kf[ct], s[rt][ct]);
    }

    // p = exp(sim); accumulate denominator; stash bf16 p in per-wave LDS
#pragma unroll
    for (int rt = 0; rt < 2; ++rt) {
      float dsum[4] = {0.f, 0.f, 0.f, 0.f};
#pragma unroll
      for (int ct = 0; ct < 8; ++ct) {
        int col = ct * 16 + (lane & 15);
        float kq = ksq_l[col];
#pragma unroll
        for (int r = 0; r < 4; ++r) {
          int il = rt * 16 + (lane >> 4) * 4 + r;
          float p = exp2f((2.f * s[rt][ct][r] - qsq_l[wid * 32 + il] - kq) * COEF);
          dsum[r] += p;
          p_lds[wid][il][((col >> 3) ^ (il & 7)) * 8 + (col & 7)] = f2bf(p);
        }
      }
#pragma unroll
      for (int r = 0; r < 4; ++r) {
        float v = dsum[r];
        v += __shfl_xor(v, 1); v += __shfl_xor(v, 2);
        v += __shfl_xor(v, 4); v += __shfl_xor(v, 8);
        denom[rt][r] += v;
      }
    }
    asm volatile("s_waitcnt lgkmcnt(0)" ::: "memory");
    __builtin_amdgcn_sched_barrier(0);

    // O += P V over this tile's 128 keys
#pragma unroll
    for (int ks2 = 0; ks2 < 4; ++ks2) {
      int j8 = ks2 * 4 + (lane >> 4);
      bf16x8 pf[2], vf[4];
#pragma unroll
      for (int rt = 0; rt < 2; ++rt) {
        int il = rt * 16 + (lane & 15);
        pf[rt] = __builtin_bit_cast(bf16x8, *(const u16x8*)(&p_lds[wid][il][(j8 ^ (il & 7)) * 8]));
      }
#pragma unroll
      for (int dt = 0; dt < 4; ++dt) {
        int d = dt * 16 + (lane & 15);
        vf[dt] = __builtin_bit_cast(bf16x8, *(const u16x8*)(&v_lds[d][(j8 ^ (d & 15)) * 8]));
      }
#pragma unroll
      for (int rt = 0; rt < 2; ++rt)
#pragma unroll
        for (int dt = 0; dt < 4; ++dt)
          oacc[rt][dt] = mfma16(pf[rt], vf[dt], oacc[rt][dt]);
    }
    __syncthreads();
  }

  // write att[b][n][h*64+d] bf16
#pragma unroll
  for (int rt = 0; rt < 2; ++rt)
#pragma unroll
    for (int dt = 0; dt < 4; ++dt)
#pragma unroll
      for (int r = 0; r < 4; ++r) {
        int i = n0 + wid * 32 + rt * 16 + (lane >> 4) * 4 + r;
        int d = dt * 16 + (lane & 15);
        att[((size_t)(b * 1024 + i)) * 512 + h * 64 + d] = f2bf(oacc[rt][dt][r] / denom[rt][r]);
      }
}

extern "C" void kernel_launch(void* const* d_in, const int* in_sizes, int n_in,
                              void* d_out, int out_size, void* d_ws, size_t ws_size,
                              hipStream_t stream) {
  const float* fmap = (const float*)d_in[0];
  const float* gamma = (const float*)d_in[1];
  const float* wq = (const float*)d_in[2];
  const float* wv = (const float*)d_in[3];
  const float* nkv = (const float*)d_in[4];
  const float* wo = (const float*)d_in[5];
  float* out = (float*)d_out;

  // workspace carve (all bf16 stored as ushort)
  unsigned short* x_t = (unsigned short*)d_ws;        // [8192][512]
  unsigned short* qb  = x_t + (size_t)8192 * 512;     // [8192][512]  q = [b,n,o]
  unsigned short* vtb = qb  + (size_t)8192 * 512;     // [8][512][1024] v_t = [b,o,n]
  unsigned short* att = vtb + (size_t)8192 * 512;     // [8192][512]
  unsigned short* wqb = att + (size_t)8192 * 512;     // [512][512]
  unsigned short* wvb = wqb + (size_t)512 * 512;
  unsigned short* wob = wvb + (size_t)512 * 512;
  float* rn  = (float*)(wob + (size_t)512 * 512);     // [8][1024]
  float* qsq = rn + 8192;                             // [64][1024]

  cvt_k<<<128, 256, 0, stream>>>(wq, wqb, 32768);
  cvt_k<<<128, 256, 0, stream>>>(wv, wvb, 32768);
  cvt_k<<<128, 256, 0, stream>>>(wo, wob, 32768);
  rnorm_k<<<dim3(16, 8), 256, 0, stream>>>(fmap, rn);
  tnorm_k<<<dim3(16, 8, 8), dim3(64, 4), 0, stream>>>(fmap, gamma, rn, x_t);
  gemm_k<0><<<dim3(4, 64), 256, 0, stream>>>(x_t, wqb, qb);    // q
  gemm_k<1><<<dim3(4, 64), 256, 0, stream>>>(x_t, wvb, vtb);   // v transposed
  qsq_k<<<256, 256, 0, stream>>>(qb, qsq);
  attn_k<<<dim3(8, 64), 256, 0, stream>>>(qb, vtb, qsq, nkv, att);
  gemm_k<2><<<dim3(64, 4), 256, 0, stream>>>(wob, att, out);   // out proj
}

// Round 2
// 130.588 us; speedup vs baseline: 1.0869x; 1.0869x over previous
//
#include <hip/hip_runtime.h>
#include <hip/hip_bf16.h>

#define DEV static __device__ __forceinline__

typedef __bf16 bf16x8 __attribute__((ext_vector_type(8)));
typedef float f32x4 __attribute__((ext_vector_type(4)));
typedef float f32x16 __attribute__((ext_vector_type(16)));
typedef unsigned u32x4 __attribute__((ext_vector_type(4)));
typedef unsigned short u16x8 __attribute__((ext_vector_type(8)));
typedef unsigned short u16x4 __attribute__((ext_vector_type(4)));

DEV unsigned short f2bf(float f) {
  unsigned u = __builtin_bit_cast(unsigned, f);
  u += 0x7fffu + ((u >> 16) & 1u);
  return (unsigned short)(u >> 16);
}
DEV float bf2f(unsigned short s) {
  return __builtin_bit_cast(float, (unsigned)s << 16);
}
DEV f32x4 mfma16(bf16x8 a, bf16x8 b, f32x4 c) {
  return __builtin_amdgcn_mfma_f32_16x16x32_bf16(a, b, c, 0, 0, 0);
}
DEV f32x16 mfma32(bf16x8 a, bf16x8 b, f32x16 c) {
  return __builtin_amdgcn_mfma_f32_32x32x16_bf16(a, b, c, 0, 0, 0);
}

// ---------------- stage 1: channel L2 norm reciprocal ----------------
__global__ __launch_bounds__(256) void rnorm_k(const float* __restrict__ fmap,
                                               float* __restrict__ rn) {
  int tid = threadIdx.x;
  int nl = tid & 63, cq = tid >> 6;
  int b = blockIdx.y;
  int n = blockIdx.x * 64 + nl;
  const float* p = fmap + ((size_t)(b * 512 + cq * 128)) * 1024 + n;
  float s = 0.f;
#pragma unroll 8
  for (int i = 0; i < 128; ++i) { float v = p[i * 1024]; s += v * v; }
  __shared__ float red[4][64];
  red[cq][nl] = s;
  __syncthreads();
  if (tid < 64) {
    float t = red[0][tid] + red[1][tid] + red[2][tid] + red[3][tid];
    rn[b * 1024 + blockIdx.x * 64 + tid] = 22.62741699796952f / fmaxf(sqrtf(t), 1e-12f);
  }
}

// ---------------- stage 2: normalize + transpose to [b,n,c] bf16 ----------------
__global__ __launch_bounds__(256) void tnorm_k(const float* __restrict__ fmap,
                                               const float* __restrict__ gamma,
                                               const float* __restrict__ rn,
                                               unsigned short* __restrict__ xt) {
  int b = blockIdx.z, c0 = blockIdx.y * 64, n0 = blockIdx.x * 64;
  __shared__ float t[64][65];
  int tx = threadIdx.x, ty = threadIdx.y;  // 64 x 4
#pragma unroll
  for (int i = 0; i < 16; ++i) {
    int r = ty * 16 + i;  // c-local
    t[r][tx] = fmap[((size_t)(b * 512 + c0 + r)) * 1024 + n0 + tx];
  }
  __syncthreads();
  float g = gamma[c0 + tx];
#pragma unroll
  for (int i = 0; i < 16; ++i) {
    int r = ty * 16 + i;  // n-local
    float val = t[tx][r] * rn[b * 1024 + n0 + r] * g;
    xt[((size_t)(b * 1024 + n0 + r)) * 512 + c0 + tx] = f2bf(val);
  }
}

// ---------------- weight f32 -> bf16 ----------------
__global__ __launch_bounds__(256) void cvt_k(const float* __restrict__ src,
                                             unsigned short* __restrict__ dst, int n8) {
  int i = blockIdx.x * 256 + threadIdx.x;
  if (i >= n8) return;
  const float4* s = (const float4*)src;
  float4 a = s[i * 2], b = s[i * 2 + 1];
  u16x8 o;
  o[0] = f2bf(a.x); o[1] = f2bf(a.y); o[2] = f2bf(a.z); o[3] = f2bf(a.w);
  o[4] = f2bf(b.x); o[5] = f2bf(b.y); o[6] = f2bf(b.z); o[7] = f2bf(b.w);
  ((u16x8*)dst)[i] = o;
}

// ---------------- generic 128x128x512 bf16 GEMM (see round-1 notes) ----------------
template <int MODE>
__global__ __launch_bounds__(256) void gemm_k(const unsigned short* __restrict__ A,
                                              const unsigned short* __restrict__ Bt,
                                              void* __restrict__ Cout) {
  __shared__ unsigned short a_lds[128][72];
  __shared__ unsigned short b_lds[128][72];
  int tid = threadIdx.x, lane = tid & 63, wid = tid >> 6;
  int wr = wid >> 1, wc = wid & 1;
  int m0 = blockIdx.y * 128, n0 = blockIdx.x * 128;
  f32x4 acc[4][4] = {};
  for (int kt = 0; kt < 512; kt += 64) {
#pragma unroll
    for (int it = 0; it < 4; ++it) {
      int chunk = it * 256 + tid;           // 0..1023
      int row = chunk >> 3, col = (chunk & 7) * 8;
      *(u16x8*)(&a_lds[row][col]) = *(const u16x8*)(A + (size_t)(m0 + row) * 512 + kt + col);
      *(u16x8*)(&b_lds[row][col]) = *(const u16x8*)(Bt + (size_t)(n0 + row) * 512 + kt + col);
    }
    __syncthreads();
#pragma unroll
    for (int ks = 0; ks < 2; ++ks) {
      bf16x8 af[4], bfr[4];
#pragma unroll
      for (int rt = 0; rt < 4; ++rt)
        af[rt] = __builtin_bit_cast(bf16x8,
            *(const u16x8*)(&a_lds[wr * 64 + rt * 16 + (lane & 15)][ks * 32 + (lane >> 4) * 8]));
#pragma unroll
      for (int ct = 0; ct < 4; ++ct)
        bfr[ct] = __builtin_bit_cast(bf16x8,
            *(const u16x8*)(&b_lds[wc * 64 + ct * 16 + (lane & 15)][ks * 32 + (lane >> 4) * 8]));
#pragma unroll
      for (int rt = 0; rt < 4; ++rt)
#pragma unroll
        for (int ct = 0; ct < 4; ++ct)
          acc[rt][ct] = mfma16(af[rt], bfr[ct], acc[rt][ct]);
    }
    __syncthreads();
  }
  if (MODE == 0) {
    unsigned short* Cp = (unsigned short*)Cout;
#pragma unroll
    for (int rt = 0; rt < 4; ++rt)
#pragma unroll
      for (int ct = 0; ct < 4; ++ct)
#pragma unroll
        for (int r = 0; r < 4; ++r) {
          int row = m0 + wr * 64 + rt * 16 + (lane >> 4) * 4 + r;
          int col = n0 + wc * 64 + ct * 16 + (lane & 15);
          Cp[(size_t)row * 512 + col] = f2bf(acc[rt][ct][r]);
        }
  } else if (MODE == 1) {
    unsigned short* Cp = (unsigned short*)Cout;
    int b = m0 >> 10;
#pragma unroll
    for (int rt = 0; rt < 4; ++rt)
#pragma unroll
      for (int ct = 0; ct < 4; ++ct) {
        int col = n0 + wc * 64 + ct * 16 + (lane & 15);
        int rowb = (m0 & 1023) + wr * 64 + rt * 16 + (lane >> 4) * 4;
        u16x4 pk;
#pragma unroll
        for (int r = 0; r < 4; ++r) pk[r] = f2bf(acc[rt][ct][r]);
        *(u16x4*)(Cp + ((size_t)(b * 512 + col)) * 1024 + rowb) = pk;
      }
  } else {
    float* Cp = (float*)Cout;
    int bb = n0 >> 10;
#pragma unroll
    for (int rt = 0; rt < 4; ++rt)
#pragma unroll
      for (int ct = 0; ct < 4; ++ct)
#pragma unroll
        for (int r = 0; r < 4; ++r) {
          int row = m0 + wr * 64 + rt * 16 + (lane >> 4) * 4 + r;        // c
          int col = (n0 & 1023) + wc * 64 + ct * 16 + (lane & 15);       // n
          Cp[((size_t)(bb * 512 + row)) * 1024 + col] = acc[rt][ct][r];
        }
  }
}

// ---------------- q squared norms (from the bf16 q the MFMA sees) ----------------
__global__ __launch_bounds__(256) void qsq_k(const unsigned short* __restrict__ q,
                                             float* __restrict__ qsq) {
  int idx = blockIdx.x * 256 + threadIdx.x;  // 65536 = b*h*n
  int bh = idx >> 10, n = idx & 1023;
  int b = bh >> 3, h = bh & 7;
  const unsigned short* p = q + ((size_t)(b * 1024 + n)) * 512 + h * 64;
  float s = 0.f;
#pragma unroll
  for (int c8 = 0; c8 < 8; ++c8) {
    u16x8 v = *(const u16x8*)(p + c8 * 8);
#pragma unroll
    for (int e = 0; e < 8; ++e) { float f = bf2f(v[e]); s += f * f; }
  }
  qsq[idx] = s;
}

// ---------------- fused distance-attention, 32x32 swapped-operand, barrier-free ----
// grid: 512 blocks (XCD-grouped bh), block 256 = 4 waves; wave owns 32 q-rows.
__global__ __launch_bounds__(256) void attn_k(const unsigned short* __restrict__ q,
                                              const unsigned short* __restrict__ vt,
                                              const float* __restrict__ qsq,
                                              const float* __restrict__ nkv,
                                              unsigned short* __restrict__ att) {
  const float COEF = 0.18033688011112042f;  // 0.125 * log2(e)
  const float C2 = 2.f * COEF;
  int bid = blockIdx.x;
  int s0 = bid >> 3;
  int bh = ((bid & 7) << 3) | (s0 & 7);   // blocks sharing bh land on one XCD
  int qt = s0 >> 3;
  int b = bh >> 3, h = bh & 7;
  int n0 = qt * 128;
  int tid = threadIdx.x, lane = tid & 63, wid = tid >> 6;
  int l31 = lane & 31, hi = lane >> 5;

  __shared__ __align__(16) float qsq_l[1024];   // ksq == qsq (k = q)
  __shared__ float p0_l[128];
  __shared__ float nk_l[64], nv_l[64];
  __shared__ float dn_l[4][32];

  ((float4*)qsq_l)[tid] = ((const float4*)(qsq + bh * 1024))[tid];
  if (tid < 64) nk_l[tid] = nkv[h * 64 + tid];
  else if (tid < 128) nv_l[tid - 64] = nkv[512 + h * 64 + (tid - 64)];
  __syncthreads();

  // null-token probabilities p0[i] = exp2((2 q.nk - |q|^2 - |nk|^2)*COEF)
  if (tid < 128) {
    const unsigned short* qp = q + ((size_t)(b * 1024 + n0 + tid)) * 512 + h * 64;
    float dot = 0.f, nks = 0.f;
#pragma unroll
    for (int d8 = 0; d8 < 8; ++d8) {
      u16x8 v = *(const u16x8*)(qp + d8 * 8);
#pragma unroll
      for (int e = 0; e < 8; ++e) {
        float nk = nk_l[d8 * 8 + e];
        float qv = bf2f(v[e]);
        dot += qv * nk; nks += nk * nk;
      }
    }
    p0_l[tid] = __builtin_amdgcn_exp2f((2.f * dot - qsq_l[n0 + tid] - nks) * COEF);
  }
  __syncthreads();

  int qrow = n0 + wid * 32 + l31;
  float my_qsq = qsq_l[n0 + wid * 32 + l31];

  // Q fragments (B-operand: col = q-row, k = d), held all kernel
  bf16x8 qf[4];
  const unsigned short* qbase = q + ((size_t)(b * 1024 + qrow)) * 512 + h * 64 + hi * 8;
#pragma unroll
  for (int ks = 0; ks < 4; ++ks)
    qf[ks] = __builtin_bit_cast(bf16x8, *(const u16x8*)(qbase + ks * 16));

  // O accumulators init with null-token contribution
  f32x16 oacc[2];
#pragma unroll
  for (int dh = 0; dh < 2; ++dh)
#pragma unroll
    for (int r = 0; r < 16; ++r) {
      int row = (r & 3) + 8 * (r >> 2) + 4 * hi;
      oacc[dh][r] = p0_l[wid * 32 + row] * nv_l[dh * 32 + l31];
    }

  f32x4 dsum4 = {0.f, 0.f, 0.f, 0.f};
  const unsigned short* kbase = q + ((size_t)(b * 1024)) * 512 + h * 64 + (size_t)l31 * 512 + hi * 8;
  const unsigned short* vbase = vt + ((size_t)(b * 512 + h * 64 + l31)) * 1024 + hi * 8;

  for (int j0 = 0; j0 < 1024; j0 += 32) {
    // K fragments direct from global (A-operand: row = j, k = d)
    bf16x8 kf[4];
    const unsigned short* kp = kbase + (size_t)j0 * 512;
#pragma unroll
    for (int ks = 0; ks < 4; ++ks)
      kf[ks] = __builtin_bit_cast(bf16x8, *(const u16x8*)(kp + ks * 16));
    // V fragments direct from global (B-operand: col = d, k = j)
    bf16x8 vf[2][2];
#pragma unroll
    for (int dh = 0; dh < 2; ++dh)
#pragma unroll
      for (int sj = 0; sj < 2; ++sj)
        vf[dh][sj] = __builtin_bit_cast(bf16x8,
            *(const u16x8*)(vbase + (size_t)dh * 32 * 1024 + j0 + sj * 16));
    // k^2 norms for this tile (broadcast reads)
    f32x4 ksq4[4];
#pragma unroll
    for (int m = 0; m < 4; ++m)
      ksq4[m] = *(const f32x4*)(&qsq_l[j0 + 8 * m + 4 * hi]);

    // S^T = K Q^T  (lane: col = q-row l31, row j = (r&3)+8*(r>>2)+4*hi)
    f32x16 sacc = {};
#pragma unroll
    for (int ks = 0; ks < 4; ++ks)
      sacc = mfma32(kf[ks], qf[ks], sacc);

    // softmax numerator in-register
    float p[16];
#pragma unroll
    for (int r = 0; r < 16; ++r) {
      int c = r & 3, m = r >> 2;
      p[r] = __builtin_amdgcn_exp2f(sacc[r] * C2 - (my_qsq + ksq4[m][c]) * COEF);
      dsum4[c] += p[r];
    }

    // pack to bf16 pairs: w[m][i] = (p[4m+2i], p[4m+2i+1])
    unsigned w[4][2];
#pragma unroll
    for (int m = 0; m < 4; ++m)
#pragma unroll
      for (int i = 0; i < 2; ++i)
        asm("v_cvt_pk_bf16_f32 %0, %1, %2" : "=v"(w[m][i]) : "v"(p[4 * m + 2 * i]), "v"(p[4 * m + 2 * i + 1]));

    // redistribute to PV A-fragments via permlane32_swap, then accumulate O
#pragma unroll
    for (int sj = 0; sj < 2; ++sj) {
      unsigned a0 = w[2 * sj][0], b0 = w[2 * sj + 1][0];
      unsigned a1 = w[2 * sj][1], b1 = w[2 * sj + 1][1];
      asm volatile("v_permlane32_swap_b32 %0, %1" : "+v"(a0), "+v"(b0));
      asm volatile("v_permlane32_swap_b32 %0, %1" : "+v"(a1), "+v"(b1));
      u32x4 pw; pw[0] = a0; pw[1] = a1; pw[2] = b0; pw[3] = b1;
      bf16x8 pa = __builtin_bit_cast(bf16x8, pw);
      oacc[0] = mfma32(pa, vf[0][sj], oacc[0]);
      oacc[1] = mfma32(pa, vf[1][sj], oacc[1]);
    }
  }

  // denominator: own-half partials + other half + null token; reciprocal; transpose
  float dsum = (dsum4[0] + dsum4[1]) + (dsum4[2] + dsum4[3]);
  dsum += __shfl_xor(dsum, 32);
  dsum += p0_l[wid * 32 + l31];
  float rden = 1.0f / dsum;
  if (hi == 0) dn_l[wid][l31] = rden;
  __syncthreads();

#pragma unroll
  for (int dh = 0; dh < 2; ++dh)
#pragma unroll
    for (int r = 0; r < 16; ++r) {
      int row = (r & 3) + 8 * (r >> 2) + 4 * hi;
      float o = oacc[dh][r] * dn_l[wid][row];
      att[((size_t)(b * 1024 + n0 + wid * 32 + row)) * 512 + h * 64 + dh * 32 + l31] = f2bf(o);
    }
}

extern "C" void kernel_launch(void* const* d_in, const int* in_sizes, int n_in,
                              void* d_out, int out_size, void* d_ws, size_t ws_size,
                              hipStream_t stream) {
  const float* fmap = (const float*)d_in[0];
  const float* gamma = (const float*)d_in[1];
  const float* wq = (const float*)d_in[2];
  const float* wv = (const float*)d_in[3];
  const float* nkv = (const float*)d_in[4];
  const float* wo = (const float*)d_in[5];
  float* out = (float*)d_out;

  unsigned short* x_t = (unsigned short*)d_ws;        // [8192][512]
  unsigned short* qb  = x_t + (size_t)8192 * 512;     // [8192][512]  q = [b,n,o]
  unsigned short* vtb = qb  + (size_t)8192 * 512;     // [8][512][1024] v_t = [b,o,n]
  unsigned short* att = vtb + (size_t)8192 * 512;     // [8192][512]
  unsigned short* wqb = att + (size_t)8192 * 512;     // [512][512]
  unsigned short* wvb = wqb + (size_t)512 * 512;
  unsigned short* wob = wvb + (size_t)512 * 512;
  float* rn  = (float*)(wob + (size_t)512 * 512);     // [8][1024]
  float* qsq = rn + 8192;                             // [64][1024]

  cvt_k<<<128, 256, 0, stream>>>(wq, wqb, 32768);
  cvt_k<<<128, 256, 0, stream>>>(wv, wvb, 32768);
  cvt_k<<<128, 256, 0, stream>>>(wo, wob, 32768);
  rnorm_k<<<dim3(16, 8), 256, 0, stream>>>(fmap, rn);
  tnorm_k<<<dim3(16, 8, 8), dim3(64, 4), 0, stream>>>(fmap, gamma, rn, x_t);
  gemm_k<0><<<dim3(4, 64), 256, 0, stream>>>(x_t, wqb, qb);    // q
  gemm_k<1><<<dim3(4, 64), 256, 0, stream>>>(x_t, wvb, vtb);   // v transposed
  qsq_k<<<256, 256, 0, stream>>>(qb, qsq);
  attn_k<<<512, 256, 0, stream>>>(qb, vtb, qsq, nkv, att);
  gemm_k<2><<<dim3(64, 4), 256, 0, stream>>>(wob, att, out);   // out proj
}